// Round 5
// baseline (195.091 us; speedup 1.0000x reference)
//
#include <hip/hip_runtime.h>
#include <hip/hip_bf16.h>
#include <math.h>

// Problem constants
#define BATCH 256
#define CIN 3
#define HW 128
#define OC 16
#define POOLED 63          // pooled spatial dim
#define FEAT 63504         // OC*63*63
#define NH 256
#define FANIN 512
#define NO 10
#define CHW (CIN*HW*HW)    // 49152

// ---------------- Kernel 1: transpose inputs (B, CHW) -> (CHW, B), float4 both sides
__global__ __launch_bounds__(256) void transpose_kernel(const float* __restrict__ in,
                                                        float* __restrict__ out) {
    __shared__ float tile[64][65];   // tile[b_local][f_local]
    const int f0 = blockIdx.x * 64;
    const int b0 = blockIdx.y * 64;
    const int t  = threadIdx.x;
    // read phase: rows = b_local, float4 along f
    {
        const int r  = t >> 4;          // 0..15
        const int cg = t & 15;          // 0..15 (float4 group)
#pragma unroll
        for (int it = 0; it < 4; ++it) {
            const int bl = r + 16 * it; // 0..63
            const float4 v = *(const float4*)&in[(size_t)(b0 + bl) * CHW + f0 + cg * 4];
            tile[bl][cg * 4 + 0] = v.x;
            tile[bl][cg * 4 + 1] = v.y;
            tile[bl][cg * 4 + 2] = v.z;
            tile[bl][cg * 4 + 3] = v.w;
        }
    }
    __syncthreads();
    // write phase: rows = f_local, float4 along b
    {
        const int r = t >> 4;           // 0..15
        const int g = t & 15;           // 0..15 (b float4 group)
#pragma unroll
        for (int it = 0; it < 4; ++it) {
            const int fl = r + 16 * it; // 0..63
            float4 v;
            v.x = tile[g * 4 + 0][fl];
            v.y = tile[g * 4 + 1][fl];
            v.z = tile[g * 4 + 2][fl];
            v.w = tile[g * 4 + 3][fl];
            *(float4*)&out[(size_t)(f0 + fl) * BATCH + b0 + g * 4] = v;
        }
    }
}

// ---------------- Kernel 2: conv3x3 + bias + relu + maxpool2x2, transposed IO ----
// inT: (C, H, W, B). featsT: (FEAT, B). One block = ONE pooled pixel (i,j) and
// EIGHT output channels (blockIdx.z selects which 8); thread = b.
//
// R0-R4 lesson: the register allocator converges to ~64 VGPRs and will
// rematerialize/replay input loads to get there (R4: fence blocked
// cross-channel remat -> 84->66us, but VGPR=68 & FETCH 1.44x compulsory show
// it still chunks the 16-oc accumulator set and replays loads within a
// region). Fix: make the whole working set FIT the comfort zone. 8 oc per
// block: acc[8][2][2]=32 regs + 16-reg patch + addr ~= 55-60 VGPR -> nothing
// to rematerialize. Cost: inT patches read twice (z=0,1) -- L3-resident, ~4us
// of extra L3 traffic. FMA count unchanged. Fence kept as insurance.
__global__ __launch_bounds__(256) void conv_pool_kernel(const float* __restrict__ inT,
                                                        const float* __restrict__ cw,
                                                        const float* __restrict__ cb,
                                                        float* __restrict__ featsT) {
    const int b  = threadIdx.x;
    const int j  = blockIdx.x;      // 0..62 pooled col
    const int i  = blockIdx.y;      // 0..62 pooled row
    const int oc0 = blockIdx.z * 8; // 0 or 8
    const int x0 = 2 * j;           // input cols x0..x0+3
    const int y0 = 2 * i;           // input rows y0..y0+3

    float acc[8][2][2];
#pragma unroll
    for (int o = 0; o < 8; ++o) {
        acc[o][0][0] = 0.f; acc[o][0][1] = 0.f;
        acc[o][1][0] = 0.f; acc[o][1][1] = 0.f;
    }

    const float* base = inT + b;
#pragma unroll
    for (int c = 0; c < CIN; ++c) {
        // 4x4 input patch for this channel: 16 regs, consumed by the FMA
        // block below, dead afterwards.
        float V[4][4];
#pragma unroll
        for (int dy = 0; dy < 4; ++dy)
#pragma unroll
            for (int dx = 0; dx < 4; ++dx)
                V[dy][dx] =
                    base[(size_t)((c * HW + (y0 + dy)) * HW + (x0 + dx)) * BATCH];

        // Fence: loads above may not be replayed below this point.
        asm volatile("" ::: "memory");

#pragma unroll
        for (int ky = 0; ky < 3; ++ky)
#pragma unroll
            for (int kx = 0; kx < 3; ++kx)
#pragma unroll
                for (int o = 0; o < 8; ++o) {
                    const float w = cw[(((oc0 + o) * CIN + c) * 3 + ky) * 3 + kx];
                    acc[o][0][0] += w * V[ky    ][kx    ];
                    acc[o][0][1] += w * V[ky    ][kx + 1];
                    acc[o][1][0] += w * V[ky + 1][kx    ];
                    acc[o][1][1] += w * V[ky + 1][kx + 1];
                }
    }

#pragma unroll
    for (int o = 0; o < 8; ++o) {
        const float m = fmaxf(fmaxf(acc[o][0][0], acc[o][0][1]),
                              fmaxf(acc[o][1][0], acc[o][1][1]));
        const float r = fmaxf(m + cb[oc0 + o], 0.0f);
        featsT[(size_t)((oc0 + o) * 3969 + i * POOLED + j) * BATCH + b] = r;
    }
}

// ---------------- Kernel 3: sparse hidden layer, transposed ----------------------
// hiddenT: (NH, B). Block = one h; 1024 threads = 4 k-splits x 256 b.
// idx/weights staged in LDS so the gather loop pipelines.
__global__ __launch_bounds__(1024, 4) void hidden_kernel(const float* __restrict__ featsT,
                                                         const int* __restrict__ hidx,
                                                         const float* __restrict__ hw,
                                                         const float* __restrict__ hb,
                                                         float* __restrict__ hiddenT) {
    __shared__ int   sidx[FANIN];
    __shared__ float swt[FANIN];
    __shared__ float red[1024];
    const int h  = blockIdx.x;
    const int t  = threadIdx.x;
    if (t < FANIN) {
        sidx[t] = hidx[h * FANIN + t];
        swt[t]  = hw[h * FANIN + t];
    }
    __syncthreads();
    const int b  = t & 255;
    const int ks = t >> 8;          // 0..3
    const int k0 = ks * 128;
    float acc = 0.f;
#pragma unroll 16
    for (int kk = 0; kk < 128; ++kk) {
        const int k = k0 + kk;
        acc += featsT[(size_t)sidx[k] * BATCH + b] * swt[k];
    }
    red[t] = acc;
    __syncthreads();
    if (t < 256) {
        float s = red[t] + red[t + 256] + red[t + 512] + red[t + 768] + hb[h];
        hiddenT[h * BATCH + b] = 1.0f / (1.0f + __expf(-s));
    }
}

// ---------------- Kernel 4: dense 256->10 output layer ---------------------------
__global__ __launch_bounds__(256) void out_kernel(const float* __restrict__ hiddenT,
                                                  const float* __restrict__ ow,
                                                  const float* __restrict__ ob,
                                                  float* __restrict__ out) {
    const int o = blockIdx.x;       // 0..9
    const int b = threadIdx.x;      // 0..255
    float a0 = 0.f, a1 = 0.f, a2 = 0.f, a3 = 0.f;
#pragma unroll 16
    for (int h = 0; h < NH; h += 4) {
        a0 += hiddenT[(h + 0) * BATCH + b] * ow[o * NH + h + 0];
        a1 += hiddenT[(h + 1) * BATCH + b] * ow[o * NH + h + 1];
        a2 += hiddenT[(h + 2) * BATCH + b] * ow[o * NH + h + 2];
        a3 += hiddenT[(h + 3) * BATCH + b] * ow[o * NH + h + 3];
    }
    float acc = (a0 + a1) + (a2 + a3);
    out[b * NO + o] = 1.0f / (1.0f + __expf(-(acc + ob[o])));
}

extern "C" void kernel_launch(void* const* d_in, const int* in_sizes, int n_in,
                              void* d_out, int out_size, void* d_ws, size_t ws_size,
                              hipStream_t stream) {
    const float* inputs   = (const float*)d_in[0];
    const float* conv_w   = (const float*)d_in[1];
    const float* conv_b   = (const float*)d_in[2];
    const int*   hidden_i = (const int*)d_in[3];
    const float* hidden_w = (const float*)d_in[4];
    const float* hidden_b = (const float*)d_in[5];
    const float* out_w    = (const float*)d_in[6];
    const float* out_b    = (const float*)d_in[7];
    float* out = (float*)d_out;

    char* ws = (char*)d_ws;
    float* inT     = (float*)ws;                                    // 50,331,648 B
    float* featsT  = (float*)(ws + (size_t)CHW * BATCH * 4);        // 65,028,096 B
    float* hiddenT = (float*)(ws + (size_t)CHW * BATCH * 4
                                 + (size_t)FEAT * BATCH * 4);       //    262,144 B

    transpose_kernel<<<dim3(CHW / 64, BATCH / 64), 256, 0, stream>>>(inputs, inT);
    conv_pool_kernel<<<dim3(63, 63, 2), 256, 0, stream>>>(inT, conv_w, conv_b, featsT);
    hidden_kernel<<<NH, 1024, 0, stream>>>(featsT, hidden_i, hidden_w, hidden_b, hiddenT);
    out_kernel<<<NO, 256, 0, stream>>>(hiddenT, out_w, out_b, out);
}

// Round 6
// 190.620 us; speedup vs baseline: 1.0235x; 1.0235x over previous
//
#include <hip/hip_runtime.h>
#include <hip/hip_bf16.h>
#include <math.h>

// Problem constants
#define BATCH 256
#define CIN 3
#define HW 128
#define OC 16
#define POOLED 63          // pooled spatial dim
#define FEAT 63504         // OC*63*63
#define NH 256
#define FANIN 512
#define NO 10
#define CHW (CIN*HW*HW)    // 49152

// ---------------- Kernel 1: conv3x3 + bias + relu + maxpool2x2, fused transpose --
// Reads inputs (B,C,H,W) DIRECTLY; the old standalone 100MB transpose round-trip
// (inT) is deleted. Each block = one pooled pixel (i,j), all 16 oc, thread = b.
// The block stages its 3x4x4 patch for all 256 b into LDS:
//   layout sV[c][dy][b][5] (pad 4->5 floats so read bank = (5b+dx)%32: lanes
//   b,b+32 only -> 2-way, free; write 2-way, free). 61,440 B -> 2 blocks/CU.
// Staging loads are 24 x float2 per thread (8B-aligned since x0 even); the
// cross-block 64B-line overlap is served by L2/L3 (inputs = 50MB, L3-resident).
// R0-R5 lesson: the allocator ALWAYS remats loads rather than hold a big acc
// file. With V in LDS a remat is a ~6cy ds_read, not a global load + 64b addr
// math -- the fight becomes cheap. Fence kept from R4 (best: 66us).
__global__ __launch_bounds__(256) void conv_pool_kernel(const float* __restrict__ inp,
                                                        const float* __restrict__ cw,
                                                        const float* __restrict__ cb,
                                                        float* __restrict__ featsT) {
    __shared__ float sV[CIN * 4 * 256 * 5];   // [c][dy][b][5] = 61,440 B
    const int b  = threadIdx.x;
    const int j  = blockIdx.x;      // 0..62 pooled col
    const int i  = blockIdx.y;      // 0..62 pooled row
    const int x0 = 2 * j;           // input cols x0..x0+3
    const int y0 = 2 * i;           // input rows y0..y0+3

    // ---- stage patch into LDS (fused transpose) ----
#pragma unroll
    for (int c = 0; c < CIN; ++c)
#pragma unroll
        for (int dy = 0; dy < 4; ++dy)
#pragma unroll
            for (int dxh = 0; dxh < 2; ++dxh) {
                const float2 v = *(const float2*)
                    &inp[(size_t)((b * CIN + c) * HW + (y0 + dy)) * HW + x0 + 2 * dxh];
                const int base = ((c * 4 + dy) * 256 + b) * 5 + 2 * dxh;
                sV[base + 0] = v.x;
                sV[base + 1] = v.y;
            }
    __syncthreads();

    float acc[OC][2][2];
#pragma unroll
    for (int oc = 0; oc < OC; ++oc) {
        acc[oc][0][0] = 0.f; acc[oc][0][1] = 0.f;
        acc[oc][1][0] = 0.f; acc[oc][1][1] = 0.f;
    }

#pragma unroll
    for (int c = 0; c < CIN; ++c) {
        // 4x4 patch for this channel from LDS: cheap to (re)read.
        float V[4][4];
#pragma unroll
        for (int dy = 0; dy < 4; ++dy)
#pragma unroll
            for (int dx = 0; dx < 4; ++dx)
                V[dy][dx] = sV[((c * 4 + dy) * 256 + b) * 5 + dx];

        // Fence: LDS reads above may not be replayed below this point.
        asm volatile("" ::: "memory");

#pragma unroll
        for (int ky = 0; ky < 3; ++ky)
#pragma unroll
            for (int kx = 0; kx < 3; ++kx)
#pragma unroll
                for (int oc = 0; oc < OC; ++oc) {
                    const float w = cw[((oc * CIN + c) * 3 + ky) * 3 + kx];
                    acc[oc][0][0] += w * V[ky    ][kx    ];
                    acc[oc][0][1] += w * V[ky    ][kx + 1];
                    acc[oc][1][0] += w * V[ky + 1][kx    ];
                    acc[oc][1][1] += w * V[ky + 1][kx + 1];
                }
    }

#pragma unroll
    for (int oc = 0; oc < OC; ++oc) {
        const float m = fmaxf(fmaxf(acc[oc][0][0], acc[oc][0][1]),
                              fmaxf(acc[oc][1][0], acc[oc][1][1]));
        const float r = fmaxf(m + cb[oc], 0.0f);
        featsT[(size_t)(oc * 3969 + i * POOLED + j) * BATCH + b] = r;
    }
}

// ---------------- Kernel 2: sparse hidden layer, transposed ----------------------
// hiddenT: (NH, B). Block = one h; 1024 threads = 4 k-splits x 256 b.
// idx/weights staged in LDS so the gather loop pipelines. (unchanged)
__global__ __launch_bounds__(1024, 4) void hidden_kernel(const float* __restrict__ featsT,
                                                         const int* __restrict__ hidx,
                                                         const float* __restrict__ hw,
                                                         const float* __restrict__ hb,
                                                         float* __restrict__ hiddenT) {
    __shared__ int   sidx[FANIN];
    __shared__ float swt[FANIN];
    __shared__ float red[1024];
    const int h  = blockIdx.x;
    const int t  = threadIdx.x;
    if (t < FANIN) {
        sidx[t] = hidx[h * FANIN + t];
        swt[t]  = hw[h * FANIN + t];
    }
    __syncthreads();
    const int b  = t & 255;
    const int ks = t >> 8;          // 0..3
    const int k0 = ks * 128;
    float acc = 0.f;
#pragma unroll 16
    for (int kk = 0; kk < 128; ++kk) {
        const int k = k0 + kk;
        acc += featsT[(size_t)sidx[k] * BATCH + b] * swt[k];
    }
    red[t] = acc;
    __syncthreads();
    if (t < 256) {
        float s = red[t] + red[t + 256] + red[t + 512] + red[t + 768] + hb[h];
        hiddenT[h * BATCH + b] = 1.0f / (1.0f + __expf(-s));
    }
}

// ---------------- Kernel 3: dense 256->10 output layer ---------------------------
// Rewritten: old version had 10 blocks (10 CUs busy, 246 idle) and a 256-deep
// serial per-thread loop. Now grid (10 o, 16 b-tiles) = 160 blocks; 256 threads
// = 16 b x 16 h-groups; each thread sums 16 h, LDS tree-reduce across groups.
__global__ __launch_bounds__(256) void out_kernel(const float* __restrict__ hiddenT,
                                                  const float* __restrict__ ow,
                                                  const float* __restrict__ ob,
                                                  float* __restrict__ out) {
    __shared__ float red[256];
    const int o  = blockIdx.x;          // 0..9
    const int bt = blockIdx.y;          // 0..15
    const int tb = threadIdx.x & 15;    // b within tile
    const int hg = threadIdx.x >> 4;    // 0..15 h-group
    const int b  = bt * 16 + tb;
    float acc = 0.f;
#pragma unroll
    for (int k = 0; k < 16; ++k) {
        const int h = hg * 16 + k;
        acc += hiddenT[h * BATCH + b] * ow[o * NH + h];
    }
    red[threadIdx.x] = acc;
    __syncthreads();
    if (hg == 0) {
        float s = 0.f;
#pragma unroll
        for (int g = 0; g < 16; ++g) s += red[g * 16 + tb];
        out[b * NO + o] = 1.0f / (1.0f + __expf(-(s + ob[o])));
    }
}

extern "C" void kernel_launch(void* const* d_in, const int* in_sizes, int n_in,
                              void* d_out, int out_size, void* d_ws, size_t ws_size,
                              hipStream_t stream) {
    const float* inputs   = (const float*)d_in[0];
    const float* conv_w   = (const float*)d_in[1];
    const float* conv_b   = (const float*)d_in[2];
    const int*   hidden_i = (const int*)d_in[3];
    const float* hidden_w = (const float*)d_in[4];
    const float* hidden_b = (const float*)d_in[5];
    const float* out_w    = (const float*)d_in[6];
    const float* out_b    = (const float*)d_in[7];
    float* out = (float*)d_out;

    char* ws = (char*)d_ws;
    float* featsT  = (float*)ws;                                    // 65,028,096 B
    float* hiddenT = (float*)(ws + (size_t)FEAT * BATCH * 4);       //    262,144 B

    conv_pool_kernel<<<dim3(63, 63), 256, 0, stream>>>(inputs, conv_w, conv_b, featsT);
    hidden_kernel<<<NH, 1024, 0, stream>>>(featsT, hidden_i, hidden_w, hidden_b, hiddenT);
    out_kernel<<<dim3(NO, 16), 256, 0, stream>>>(hiddenT, out_w, out_b, out);
}

// Round 7
// 171.731 us; speedup vs baseline: 1.1360x; 1.1100x over previous
//
#include <hip/hip_runtime.h>
#include <hip/hip_bf16.h>
#include <math.h>

// Problem constants
#define BATCH 256
#define CIN 3
#define HW 128
#define OC 16
#define POOLED 63          // pooled spatial dim
#define FEAT 63504         // OC*63*63
#define NH 256
#define FANIN 512
#define NO 10
#define CHW (CIN*HW*HW)    // 49152

// ---------------- Kernel 1: conv3x3 + bias + relu + maxpool2x2, fused transpose --
// R6 post-mortem: fused staging with block=(i,j) forced per-lane 8B gathers at
// 196KB stride -> FETCH 200MB (4x input), HBM-bound, 110us. Fix: block =
// (pooled row i, 8-batch tile). Stage rows y0..y0+3 x 3c x 8b x 128x into LDS
// with FULLY COALESCED reads: 12 float4/thread, 32 consecutive lanes = 512
// contiguous bytes. Each input row-line reused by block i+1 (x2, L3-absorbed).
// LDS row stride 130 floats (pad +2): byte stride 520 -> read bank shift 2/row,
// <=2-way conflicts (free). 49,920B LDS -> 3 blocks/CU, 12 waves/CU.
// Compute: 504 items (b_l 0..7, j 0..62) over 256 threads, ~2 items/thread;
// per-item body = R6's proven compute (V[4][4] per c + fence + 16-oc FMA).
__global__ __launch_bounds__(256) void conv_pool_kernel(const float* __restrict__ inp,
                                                        const float* __restrict__ cw,
                                                        const float* __restrict__ cb,
                                                        float* __restrict__ featsT) {
    __shared__ float sV[96 * 130];            // [ (c*4+dy)*8 + b_l ][130] = 49,920 B
    const int t  = threadIdx.x;
    const int i  = blockIdx.x;      // 0..62 pooled row
    const int b0 = blockIdx.y * 8;  // batch tile base
    const int y0 = 2 * i;           // input rows y0..y0+3

    // ---- stage: 3072 float4 total, 12 per thread, coalesced along x ----
#pragma unroll
    for (int it = 0; it < 12; ++it) {
        const int q  = t + 256 * it;     // 0..3071
        const int r  = q >> 5;           // row id 0..95
        const int x4 = q & 31;           // float4 index within row
        const int b_l = r / 12;
        const int rem = r % 12;
        const int c   = rem >> 2;
        const int dy  = rem & 3;
        const float4 v = *(const float4*)
            &inp[((size_t)(b0 + b_l) * CIN + c) * (HW * HW) + (y0 + dy) * HW + 4 * x4];
        const int base = ((c * 4 + dy) * 8 + b_l) * 130 + 4 * x4;
        sV[base + 0] = v.x;
        sV[base + 1] = v.y;
        sV[base + 2] = v.z;
        sV[base + 3] = v.w;
    }
    __syncthreads();

    // ---- compute: items m = t and t+256; item -> j = m>>3, b_l = m&7 ----
    for (int m = t; m < 504; m += 256) {
        const int j   = m >> 3;          // 0..62
        const int b_l = m & 7;
        const int x0  = 2 * j;

        float acc[OC][2][2];
#pragma unroll
        for (int oc = 0; oc < OC; ++oc) {
            acc[oc][0][0] = 0.f; acc[oc][0][1] = 0.f;
            acc[oc][1][0] = 0.f; acc[oc][1][1] = 0.f;
        }

#pragma unroll
        for (int c = 0; c < CIN; ++c) {
            float V[4][4];
#pragma unroll
            for (int dy = 0; dy < 4; ++dy)
#pragma unroll
                for (int dx = 0; dx < 4; ++dx)
                    V[dy][dx] = sV[((c * 4 + dy) * 8 + b_l) * 130 + x0 + dx];

            // Fence: LDS reads above may not be replayed below this point.
            asm volatile("" ::: "memory");

#pragma unroll
            for (int ky = 0; ky < 3; ++ky)
#pragma unroll
                for (int kx = 0; kx < 3; ++kx)
#pragma unroll
                    for (int oc = 0; oc < OC; ++oc) {
                        const float w = cw[((oc * CIN + c) * 3 + ky) * 3 + kx];
                        acc[oc][0][0] += w * V[ky    ][kx    ];
                        acc[oc][0][1] += w * V[ky    ][kx + 1];
                        acc[oc][1][0] += w * V[ky + 1][kx    ];
                        acc[oc][1][1] += w * V[ky + 1][kx + 1];
                    }
        }

#pragma unroll
        for (int oc = 0; oc < OC; ++oc) {
            const float mx = fmaxf(fmaxf(acc[oc][0][0], acc[oc][0][1]),
                                   fmaxf(acc[oc][1][0], acc[oc][1][1]));
            const float rr = fmaxf(mx + cb[oc], 0.0f);
            featsT[(size_t)(oc * 3969 + i * POOLED + j) * BATCH + b0 + b_l] = rr;
        }
    }
}

// ---------------- Kernel 2: sparse hidden layer, transposed ----------------------
// hiddenT: (NH, B). Block = one h; 1024 threads = 4 k-splits x 256 b.
// idx/weights staged in LDS so the gather loop pipelines. (unchanged)
__global__ __launch_bounds__(1024, 4) void hidden_kernel(const float* __restrict__ featsT,
                                                         const int* __restrict__ hidx,
                                                         const float* __restrict__ hw,
                                                         const float* __restrict__ hb,
                                                         float* __restrict__ hiddenT) {
    __shared__ int   sidx[FANIN];
    __shared__ float swt[FANIN];
    __shared__ float red[1024];
    const int h  = blockIdx.x;
    const int t  = threadIdx.x;
    if (t < FANIN) {
        sidx[t] = hidx[h * FANIN + t];
        swt[t]  = hw[h * FANIN + t];
    }
    __syncthreads();
    const int b  = t & 255;
    const int ks = t >> 8;          // 0..3
    const int k0 = ks * 128;
    float acc = 0.f;
#pragma unroll 16
    for (int kk = 0; kk < 128; ++kk) {
        const int k = k0 + kk;
        acc += featsT[(size_t)sidx[k] * BATCH + b] * swt[k];
    }
    red[t] = acc;
    __syncthreads();
    if (t < 256) {
        float s = red[t] + red[t + 256] + red[t + 512] + red[t + 768] + hb[h];
        hiddenT[h * BATCH + b] = 1.0f / (1.0f + __expf(-s));
    }
}

// ---------------- Kernel 3: dense 256->10 output layer ---------------------------
// grid (10 o, 16 b-tiles) = 160 blocks; 256 threads = 16 b x 16 h-groups;
// each thread sums 16 h, LDS tree-reduce across groups. (unchanged)
__global__ __launch_bounds__(256) void out_kernel(const float* __restrict__ hiddenT,
                                                  const float* __restrict__ ow,
                                                  const float* __restrict__ ob,
                                                  float* __restrict__ out) {
    __shared__ float red[256];
    const int o  = blockIdx.x;          // 0..9
    const int bt = blockIdx.y;          // 0..15
    const int tb = threadIdx.x & 15;    // b within tile
    const int hg = threadIdx.x >> 4;    // 0..15 h-group
    const int b  = bt * 16 + tb;
    float acc = 0.f;
#pragma unroll
    for (int k = 0; k < 16; ++k) {
        const int h = hg * 16 + k;
        acc += hiddenT[h * BATCH + b] * ow[o * NH + h];
    }
    red[threadIdx.x] = acc;
    __syncthreads();
    if (hg == 0) {
        float s = 0.f;
#pragma unroll
        for (int g = 0; g < 16; ++g) s += red[g * 16 + tb];
        out[b * NO + o] = 1.0f / (1.0f + __expf(-(s + ob[o])));
    }
}

extern "C" void kernel_launch(void* const* d_in, const int* in_sizes, int n_in,
                              void* d_out, int out_size, void* d_ws, size_t ws_size,
                              hipStream_t stream) {
    const float* inputs   = (const float*)d_in[0];
    const float* conv_w   = (const float*)d_in[1];
    const float* conv_b   = (const float*)d_in[2];
    const int*   hidden_i = (const int*)d_in[3];
    const float* hidden_w = (const float*)d_in[4];
    const float* hidden_b = (const float*)d_in[5];
    const float* out_w    = (const float*)d_in[6];
    const float* out_b    = (const float*)d_in[7];
    float* out = (float*)d_out;

    char* ws = (char*)d_ws;
    float* featsT  = (float*)ws;                                    // 65,028,096 B
    float* hiddenT = (float*)(ws + (size_t)FEAT * BATCH * 4);       //    262,144 B

    conv_pool_kernel<<<dim3(63, 32), 256, 0, stream>>>(inputs, conv_w, conv_b, featsT);
    hidden_kernel<<<NH, 1024, 0, stream>>>(featsT, hidden_i, hidden_w, hidden_b, hiddenT);
    out_kernel<<<dim3(NO, 16), 256, 0, stream>>>(hiddenT, out_w, out_b, out);
}